// Round 8
// baseline (510.533 us; speedup 1.0000x reference)
//
#include <hip/hip_runtime.h>

// SumGCNEncoder: NU=NI=100000, DIN=DOUT=128, NS=5, E=500000
// pp (conv+BT+coarse-bucket place) -> binsort (row-sort per bucket, perm-flush)
// -> fused gather+GEMM at half-bin (32-row) granularity. 3 dispatches.
#define R_     100000
#define NSUP   5
#define EDGES  500000
#define D_     128
#define ND     (NSUP * D_)          // 640
#define BR     64                   // rows per bin
#define PPS2   ((R_ + BR - 1) / BR) // 1563 bins per support
#define CAP2   512                  // max edges/bin (mean 320, sigma 17.9)
#define HCAP   256                  // max edges/half-bin (mean 160, sigma 12.6)

#define EPB    4096                 // edges per placement block
#define BPS    123                  // placement blocks per (side,support)
#define NB_C   196                  // coarse buckets (512 rows each)
#define CST    128                  // coff inner stride (>= BPS)
#define CROWS  (NB_C + 1)           // 197: buckets + sentinel
#define ECAP   2944                 // max edges/(seg,bucket): mean 2560, sigma 50

#define PPB    12500                // conv blocks in pp_k
#define BTB    160                  // BT blocks in pp_k

using short8 = __attribute__((ext_vector_type(8))) short;
using f32x4  = __attribute__((ext_vector_type(4))) float;

static __device__ __forceinline__ float bf2f_lo(unsigned p) { return __uint_as_float(p << 16); }
static __device__ __forceinline__ float bf2f_hi(unsigned p) { return __uint_as_float(p & 0xffff0000u); }
static __device__ __forceinline__ unsigned short f2bf(float x) {
    unsigned u = __float_as_uint(x);
    return (unsigned short)((u + 0x7fffu + ((u >> 16) & 1u)) >> 16);  // RNE
}

// ---------------------------------------------------------------------------
// pp: heterogeneous 512-thread grid (UNCHANGED from r6).
__global__ __launch_bounds__(512) void pp_k(const float* __restrict__ user_in,
                                            const float* __restrict__ item_in,
                                            const float* __restrict__ w,
                                            const int* __restrict__ u_rows,
                                            const int* __restrict__ u_cols,
                                            const float* __restrict__ u_vals,
                                            const int* __restrict__ i_rows,
                                            const int* __restrict__ i_cols,
                                            const float* __restrict__ i_vals,
                                            unsigned short* __restrict__ srcb,
                                            unsigned short* __restrict__ bt,
                                            int* __restrict__ coff,
                                            uint2* __restrict__ cedge2) {
    __shared__ uint2 estage[EPB];      // 32 KB
    __shared__ int   hist[NB_C];       // 784 B
    __shared__ int   wsum[8];

    int b = blockIdx.x, tid = threadIdx.x;
    if (b < PPB) {
        int side = b / 6250;                        // side0 gathers ITEM feats
        int t = (b - side * 6250) * 512 + tid;      // t < 3,200,000 exact
        const float* src = side ? user_in : item_in;
        float4 v = *(const float4*)(src + (size_t)t * 4);
        ushort4 o;
        o.x = f2bf(v.x); o.y = f2bf(v.y); o.z = f2bf(v.z); o.w = f2bf(v.w);
        *(ushort4*)(srcb + (size_t)side * (R_ * D_) + (size_t)t * 4) = o;
        return;
    }
    if (b < PPB + BTB) {
        int t = (b - PPB) * 512 + tid;              // t < 81920 exact
        int o = t / ND;
        int kk = t - o * ND;
        int i = kk >> 7, d = kk & 127;
        float s = 0.f;
        for (int j = 0; j <= i; j++) s += w[(d * D_ + o) * NSUP + j];
        bt[t] = f2bf(s);
        return;
    }
    // ---- coarse place ------------------------------------------------------
    int q = b - (PPB + BTB);
    int seg = q / BPS;
    int bb  = q - seg * BPS;
    int side = seg / NSUP;
    int sup  = seg - side * NSUP;
    const int*   rows = side ? i_rows : u_rows;
    const int*   cols = side ? i_cols : u_cols;
    const float* vals = side ? i_vals : u_vals;
    int e0 = bb * EPB;
    int ecnt = EDGES - e0; if (ecnt > EPB) ecnt = EPB;
    size_t gb = (size_t)sup * EDGES + e0;

    if (tid < NB_C) hist[tid] = 0;
    __syncthreads();
    for (int e = tid; e < ecnt; e += 512)
        atomicAdd(&hist[rows[gb + e] >> 9], 1);
    __syncthreads();
    int cnt = (tid < NB_C) ? hist[tid] : 0;
    int lane = tid & 63, wv = tid >> 6;
    int s = cnt;
#pragma unroll
    for (int off = 1; off < 64; off <<= 1) {
        int u = __shfl_up(s, off, 64);
        if (lane >= off) s += u;
    }
    if (lane == 63) wsum[wv] = s;
    __syncthreads();
    int woff = 0;
#pragma unroll
    for (int k = 0; k < 8; k++) woff += (k < wv) ? wsum[k] : 0;
    int ex = woff + s - cnt;
    if (tid < NB_C) {
        coff[(size_t)(seg * CROWS + tid) * CST + bb] = ex;
        hist[tid] = ex;                           // -> cursor
    }
    if (tid == 0) coff[(size_t)(seg * CROWS + NB_C) * CST + bb] = ecnt;  // sentinel
    __syncthreads();
    for (int e = tid; e < ecnt; e += 512) {
        int r = rows[gb + e];
        int pos = atomicAdd(&hist[r >> 9], 1);
        uint2 E;
        E.x = (unsigned)cols[gb + e] | ((unsigned)(r & 511) << 17);
        E.y = __float_as_uint(vals[gb + e]);
        estage[pos] = E;
    }
    __syncthreads();
    size_t cbase = (size_t)(seg * BPS + bb) * EPB;
    for (int e = tid; e < ecnt; e += 512) cedge2[cbase + e] = estage[e];
}

// ---------------------------------------------------------------------------
// binsort (UNCHANGED from r6): one block per (seg, coarse bucket).
__global__ __launch_bounds__(512) void binsort_k(const int* __restrict__ coff,
                                                 const uint2* __restrict__ cedge2,
                                                 uint2* __restrict__ cedge3,
                                                 int* __restrict__ rtab) {
    __shared__ uint2 estage[ECAP];         // 23.5 KB raw edges
    __shared__ unsigned short perm[ECAP];  // 5.75 KB sorted->raw index
    __shared__ int hs[512];                // inclusive row scan
    __shared__ int cur[512];               // hist, then cursors
    __shared__ int rstart[BPS + 1];
    __shared__ int ro0[BPS];
    __shared__ int wsum[8];

    int q = blockIdx.x;
    int seg = q / NB_C;
    int c   = q - seg * NB_C;
    int side = seg / NSUP;
    int sup  = seg - side * NSUP;
    int tid = threadIdx.x;
    int lane = tid & 63, wv = tid >> 6;

    cur[tid] = 0;
    if (wv == 0) {
        const int* crow = coff + (size_t)(seg * CROWS + c) * CST;
        int j0 = lane * 2, j1 = j0 + 1;
        int o0 = 0, o1 = 0, c0 = 0, c1 = 0;
        if (j0 < BPS) { o0 = crow[j0]; c0 = crow[j0 + CST] - o0; }
        if (j1 < BPS) { o1 = crow[j1]; c1 = crow[j1 + CST] - o1; }
        int sc = c0 + c1;
        int s = sc;
#pragma unroll
        for (int off = 1; off < 64; off <<= 1) {
            int u = __shfl_up(s, off, 64);
            if (lane >= off) s += u;
        }
        int ex = s - sc;
        if (j0 < BPS) { rstart[j0] = ex;      ro0[j0] = o0; }
        if (j1 < BPS) { rstart[j1] = ex + c0; ro0[j1] = o1; }
        if (lane == 63) rstart[BPS] = s;
    }
    __syncthreads();
    int n = rstart[BPS]; if (n > ECAP) n = ECAP;
    if (tid < 4 * BPS) {
        int rb = tid >> 2, j0 = tid & 3;
        int rs = rstart[rb];
        int cntr = rstart[rb + 1] - rs;
        const uint2* src = cedge2 + (size_t)(seg * BPS + rb) * EPB + ro0[rb];
        for (int j = j0; j < cntr; j += 4) {
            int pos = rs + j;
            if (pos < ECAP) estage[pos] = src[j];
        }
    }
    __syncthreads();
    for (int e = tid; e < n; e += 512)
        atomicAdd(&cur[(estage[e].x >> 17) & 511], 1);
    __syncthreads();
    int cnt = cur[tid];
    int s = cnt;
#pragma unroll
    for (int off = 1; off < 64; off <<= 1) {
        int u = __shfl_up(s, off, 64);
        if (lane >= off) s += u;
    }
    if (lane == 63) wsum[wv] = s;
    __syncthreads();
    int woff = 0;
#pragma unroll
    for (int k = 0; k < 8; k++) woff += (k < wv) ? wsum[k] : 0;
    int sinc = woff + s;                  // inclusive over 512 local rows
    hs[tid] = sinc;
    cur[tid] = sinc - cnt;                // exclusive -> cursor
    __syncthreads();
    int b_ = tid >> 6;                    // bin-in-bucket
    int gbin = c * 8 + b_;
    if (gbin < PPS2) {
        int binst = b_ ? hs[(b_ << 6) - 1] : 0;
        int srel = sinc - binst; if (srel > CAP2) srel = CAP2;
        rtab[((size_t)(side * PPS2 + gbin)) * (NSUP * BR) + sup * BR + (tid & 63)] = srel;
    }
    for (int e = tid; e < n; e += 512) {
        int pos = atomicAdd(&cur[(estage[e].x >> 17) & 511], 1);
        perm[pos] = (unsigned short)e;
    }
    __syncthreads();
    size_t segbase = (size_t)(side * NSUP + sup) * PPS2;
    for (int ep = tid; ep < n; ep += 512) {
        uint2 E = estage[perm[ep]];
        int rl = (E.x >> 17) & 511;
        int b2 = rl >> 6;
        int gb2 = c * 8 + b2;
        int binst = b2 ? hs[(b2 << 6) - 1] : 0;
        int wpos = ep - binst;
        if (wpos < CAP2 && gb2 < PPS2)
            cedge3[(segbase + gb2) * CAP2 + wpos] = E;
    }
}

// ---------------------------------------------------------------------------
// Fused gather + GEMM + relu at HALF-BIN granularity: one block per
// (side, bin, 32-row half), 256 threads / 4 waves. LDS ~19.7 KB -> 8 blocks/CU
// (32 waves) for r1-class latency hiding; acc[2][2] = 16 VGPR.
// Row-sorted cedge3 makes each half's edges a contiguous slice.
// FIX vs r7: rsc_all has 320 entries but block is 256 threads -> strided load
// (r7's `if (tid < 320)` left support 4's offsets uninitialized -> OOB fault).
// Grid = 2 * PPS2 * 2 = 6252.
__global__ __launch_bounds__(256, 8) void fused_k(const uint2* __restrict__ cedge3,
                                                  const int* __restrict__ rtab,
                                                  const unsigned short* __restrict__ srcb,
                                                  const unsigned short* __restrict__ BT,
                                                  float* __restrict__ out) {
    __shared__ unsigned short stile[32 * D_];    // 8 KB (f32 ltile in epilogue)
    __shared__ uint2 eds5[NSUP * HCAP];          // 10 KB
    __shared__ int rsc_all[NSUP * BR];           // 1.25 KB (full-bin inclusive)

    int bid = blockIdx.x;
    int side = bid / (PPS2 * 2);
    int rem  = bid - side * (PPS2 * 2);
    int bin  = rem >> 1;
    int half = rem & 1;
    int hbase = half * 32;
    const unsigned short* srcbf = srcb + (size_t)side * (R_ * D_);
    float* outp = out + (size_t)side * R_ * D_;

    int tid = threadIdx.x;
    int wid = tid >> 6, lane = tid & 63;
    int g = lane >> 4, l16 = lane & 15;

    size_t rbase = ((size_t)(side * PPS2 + bin)) * (NSUP * BR);
    for (int j = tid; j < NSUP * BR; j += 256)        // 320 entries, 256 threads
        rsc_all[j] = rtab[rbase + j];
    __syncthreads();                              // rsc_all ready (needed for preload)

    // preload this half's edge slices for all 5 supports
#pragma unroll
    for (int i = 0; i < NSUP; i++) {
        int st0 = hbase ? rsc_all[i * BR + hbase - 1] : 0;
        int end = rsc_all[i * BR + hbase + 31];
        int cnt = end - st0;
        if (cnt > HCAP) cnt = HCAP;
        if (cnt < 0) cnt = 0;
        const uint2* ebase = cedge3 + (size_t)((side * NSUP + i) * PPS2 + bin) * CAP2 + st0;
        for (int e = tid; e < cnt; e += 256) eds5[i * HCAP + e] = ebase[e];
    }

    f32x4 acc[2][2];
#pragma unroll
    for (int rt = 0; rt < 2; rt++)
#pragma unroll
        for (int nt = 0; nt < 2; nt++)
            acc[rt][nt] = (f32x4){0.f, 0.f, 0.f, 0.f};

    __syncthreads();                              // B0: eds5 ready

    for (int i = 0; i < NSUP; i++) {
        const uint2* eds = eds5 + i * HCAP;
        int st0 = hbase ? rsc_all[i * BR + hbase - 1] : 0;
        // ---- gather: 16 lanes/row, uint4 gathers, unroll-4 -> stile ----------
#pragma unroll
        for (int rq = wid; rq < 8; rq += 4) {
            int r = rq * 4 + g;                   // local row 0..31
            int gr = hbase + r;
            int s0 = (gr ? rsc_all[i * BR + gr - 1] : 0) - st0;
            int e2 = rsc_all[i * BR + gr] - st0;
            if (s0 < 0) s0 = 0;
            if (e2 > HCAP) e2 = HCAP;
            float a0 = 0.f, a1 = 0.f, a2 = 0.f, a3 = 0.f;
            float a4 = 0.f, a5 = 0.f, a6 = 0.f, a7 = 0.f;
            int e = s0;
            for (; e + 3 < e2; e += 4) {
                uint2 E0 = eds[e], E1 = eds[e + 1], E2 = eds[e + 2], E3 = eds[e + 3];
                const uint4 p0 = *(const uint4*)(srcbf + (size_t)(E0.x & 0x1FFFFu) * D_ + l16 * 8);
                const uint4 p1 = *(const uint4*)(srcbf + (size_t)(E1.x & 0x1FFFFu) * D_ + l16 * 8);
                const uint4 p2 = *(const uint4*)(srcbf + (size_t)(E2.x & 0x1FFFFu) * D_ + l16 * 8);
                const uint4 p3 = *(const uint4*)(srcbf + (size_t)(E3.x & 0x1FFFFu) * D_ + l16 * 8);
                float v0 = __uint_as_float(E0.y), v1 = __uint_as_float(E1.y);
                float v2 = __uint_as_float(E2.y), v3 = __uint_as_float(E3.y);
                a0 += v0 * bf2f_lo(p0.x); a1 += v0 * bf2f_hi(p0.x);
                a2 += v0 * bf2f_lo(p0.y); a3 += v0 * bf2f_hi(p0.y);
                a4 += v0 * bf2f_lo(p0.z); a5 += v0 * bf2f_hi(p0.z);
                a6 += v0 * bf2f_lo(p0.w); a7 += v0 * bf2f_hi(p0.w);
                a0 += v1 * bf2f_lo(p1.x); a1 += v1 * bf2f_hi(p1.x);
                a2 += v1 * bf2f_lo(p1.y); a3 += v1 * bf2f_hi(p1.y);
                a4 += v1 * bf2f_lo(p1.z); a5 += v1 * bf2f_hi(p1.z);
                a6 += v1 * bf2f_lo(p1.w); a7 += v1 * bf2f_hi(p1.w);
                a0 += v2 * bf2f_lo(p2.x); a1 += v2 * bf2f_hi(p2.x);
                a2 += v2 * bf2f_lo(p2.y); a3 += v2 * bf2f_hi(p2.y);
                a4 += v2 * bf2f_lo(p2.z); a5 += v2 * bf2f_hi(p2.z);
                a6 += v2 * bf2f_lo(p2.w); a7 += v2 * bf2f_hi(p2.w);
                a0 += v3 * bf2f_lo(p3.x); a1 += v3 * bf2f_hi(p3.x);
                a2 += v3 * bf2f_lo(p3.y); a3 += v3 * bf2f_hi(p3.y);
                a4 += v3 * bf2f_lo(p3.z); a5 += v3 * bf2f_hi(p3.z);
                a6 += v3 * bf2f_lo(p3.w); a7 += v3 * bf2f_hi(p3.w);
            }
            for (; e < e2; e++) {
                uint2 E = eds[e];
                const uint4 pk = *(const uint4*)(srcbf + (size_t)(E.x & 0x1FFFFu) * D_ + l16 * 8);
                float vv = __uint_as_float(E.y);
                a0 += vv * bf2f_lo(pk.x); a1 += vv * bf2f_hi(pk.x);
                a2 += vv * bf2f_lo(pk.y); a3 += vv * bf2f_hi(pk.y);
                a4 += vv * bf2f_lo(pk.z); a5 += vv * bf2f_hi(pk.z);
                a6 += vv * bf2f_lo(pk.w); a7 += vv * bf2f_hi(pk.w);
            }
            uint4 P;
            P.x = ((unsigned)f2bf(a1) << 16) | f2bf(a0);
            P.y = ((unsigned)f2bf(a3) << 16) | f2bf(a2);
            P.z = ((unsigned)f2bf(a5) << 16) | f2bf(a4);
            P.w = ((unsigned)f2bf(a7) << 16) | f2bf(a6);
            int boff = r * 256 + ((l16 * 16) ^ ((r & 7) << 4));   // XOR swizzle
            *(uint4*)((char*)stile + boff) = P;
        }
        __syncthreads();                          // gather done, stile ready

        // ---- MFMA: wave wid owns out-cols [wid*32, wid*32+32) -----------------
        const unsigned short* btp0 = BT + (size_t)(wid * 32 + l16) * ND + i * D_;
#pragma unroll
        for (int cc = 0; cc < 4; cc++) {
#pragma unroll
            for (int nt = 0; nt < 2; nt++) {
                short8 bfr = *(const short8*)(btp0 + (size_t)(nt * 16) * ND + cc * 32 + g * 8);
#pragma unroll
                for (int rt = 0; rt < 2; rt++) {
                    int row = rt * 16 + l16;
                    int boff = row * 256 + ((cc * 64 + g * 16) ^ ((row & 7) << 4));
                    short8 afr = *(const short8*)((const char*)stile + boff);
                    acc[rt][nt] = __builtin_amdgcn_mfma_f32_16x16x32_bf16(afr, bfr,
                                                                          acc[rt][nt], 0, 0, 0);
                }
            }
        }
        __syncthreads();                          // MFMA done, stile reusable
    }

    // ---- epilogue: stage 16-row f32 slabs in LDS, full-line stores ------------
    float* ltile = (float*)stile;
#pragma unroll
    for (int p = 0; p < 2; p++) {                 // rows [p*16, p*16+16)
#pragma unroll
        for (int nt = 0; nt < 2; nt++) {
#pragma unroll
            for (int rr = 0; rr < 4; rr++) {
                int lr = g * 4 + rr;              // 0..15
                float v = acc[p][nt][rr];
                v = v > 0.f ? v : 0.f;
                int col = wid * 32 + nt * 16 + l16;
                *(float*)((char*)ltile + lr * 512 + ((col * 4) ^ ((lr & 7) << 4))) = v;
            }
        }
        __syncthreads();                          // ltile ready
#pragma unroll
        for (int s = 0; s < 2; s++) {
            int idx = tid + s * 256;
            int lr = idx >> 5, c4 = idx & 31;
            int grow = bin * BR + hbase + p * 16 + lr;
            if (grow < R_) {
                float4 v = *(const float4*)((const char*)ltile + lr * 512 +
                                            ((c4 * 16) ^ ((lr & 7) << 4)));
                *(float4*)(outp + (size_t)grow * D_ + c4 * 4) = v;
            }
        }
        __syncthreads();                          // stores drained before reuse
    }
}

// ---------------------------------------------------------------------------
extern "C" void kernel_launch(void* const* d_in, const int* in_sizes, int n_in,
                              void* d_out, int out_size, void* d_ws, size_t ws_size,
                              hipStream_t stream) {
    const float* user_in = (const float*)d_in[0];
    const float* item_in = (const float*)d_in[1];
    const float* weight  = (const float*)d_in[2];
    const int* u_rows = (const int*)d_in[3];
    const int* u_cols = (const int*)d_in[4];
    const float* u_vals = (const float*)d_in[5];
    const int* i_rows = (const int*)d_in[6];
    const int* i_cols = (const int*)d_in[7];
    const float* i_vals = (const float*)d_in[8];
    float* out = (float*)d_out;

    // ws layout (bytes), total ~160.7 MB
    char* ws = (char*)d_ws;
    unsigned short* srcb = (unsigned short*)(ws);               // 2*100000*128*2 = 51,200,000
    unsigned short* BT   = (unsigned short*)(ws + 51200000);    // 128*640*2      = 163,840
    uint2* cedge2        = (uint2*)         (ws + 51363840);    // 1230*4096*8    = 40,304,640
    int*   coff          = (int*)           (ws + 91668480);    // 10*197*128*4   = 1,008,640
    uint2* cedge3        = (uint2*)         (ws + 92677120);    // 15630*512*8    = 64,020,480
    int*   rtab          = (int*)           (ws + 156697600);   // 2*1563*320*4   = 4,001,280

    pp_k<<<PPB + BTB + 10 * BPS, 512, 0, stream>>>(user_in, item_in, weight,
                                                   u_rows, u_cols, u_vals,
                                                   i_rows, i_cols, i_vals,
                                                   srcb, BT, coff, cedge2);
    binsort_k<<<10 * NB_C, 512, 0, stream>>>(coff, cedge2, cedge3, rtab);
    fused_k<<<2 * PPS2 * 2, 256, 0, stream>>>(cedge3, rtab, srcb, BT, out);
}